// Round 15
// baseline (383.491 us; speedup 1.0000x reference)
//
#include <hip/hip_runtime.h>

typedef __bf16 bf16x8 __attribute__((ext_vector_type(8)));
typedef float f32x16 __attribute__((ext_vector_type(16)));

constexpr int K1 = 4096;
constexpr int N1 = 512;
constexpr int TT = 64;
constexpr int NC = 40;
constexpr float EPS  = 1e-4f;
constexpr float EPS2 = 1e-5f;
constexpr unsigned CAP  = 8192;
constexpr unsigned CAP2 = 1024;

// ws layout (bytes) — high-water 50.46 MB (proven)
constexpr size_t S_OFF    = 0;
constexpr size_t W1T_OFF  = 33554432;
constexpr size_t PKH_OFF  = 41943040;
constexpr size_t PKM_OFF  = 46137344;
constexpr size_t CNT_OFF  = 50331648;
constexpr size_t LIST_OFF = 50331904;
constexpr size_t YFIX_OFF  = PKH_OFF;
constexpr size_t W2PK_OFF  = PKM_OFF;
constexpr size_t SSUM_OFF  = PKM_OFF + 196608;
constexpr size_t LIST2_OFF = PKM_OFF + 237568;

union U8 { ushort u[8]; uint4 v; };
union BC { __bf16 b; ushort s; };

__device__ __forceinline__ void split_pair(float f0, float f1,
                                           unsigned& hp, unsigned& mp) {
  asm("v_cvt_pk_bf16_f32 %0, %1, %2" : "=v"(hp) : "v"(f0), "v"(f1));
  unsigned h0b = hp << 16;
  unsigned h1b = hp & 0xFFFF0000u;
  float m0 = f0 - __builtin_bit_cast(float, h0b);
  float m1 = f1 - __builtin_bit_cast(float, h1b);
  asm("v_cvt_pk_bf16_f32 %0, %1, %2" : "=v"(mp) : "v"(m0), "v"(m1));
}

// ---------------------------------------------------------------------------
// prep: W1 -> W1T (f32 [n][k]) + MFMA B-frag-ordered bf16 hi/mid packs.
// ---------------------------------------------------------------------------
__global__ __launch_bounds__(256) void prep(const float* __restrict__ W1,
                                            float* __restrict__ W1T,
                                            uint4* __restrict__ pkh,
                                            uint4* __restrict__ pkm) {
  __shared__ float tile[64][65];
  const int tid = threadIdx.x;
  const int kb = blockIdx.x * 64;
  const int nb = blockIdx.y * 64;
  const int r  = tid >> 2;
  const int c0 = (tid & 3) * 16;
  const float4* src = (const float4*)(W1 + (size_t)(kb + r) * N1 + nb + c0);
#pragma unroll
  for (int u = 0; u < 4; ++u) {
    float4 v = src[u];
    tile[r][c0 + u * 4 + 0] = v.x;
    tile[r][c0 + u * 4 + 1] = v.y;
    tile[r][c0 + u * 4 + 2] = v.z;
    tile[r][c0 + u * 4 + 3] = v.w;
  }
  __syncthreads();
  const size_t ob = (size_t)(nb + r) * K1 + kb + c0;
#pragma unroll
  for (int u = 0; u < 4; ++u) {
    float4 o = make_float4(tile[c0 + u * 4 + 0][r], tile[c0 + u * 4 + 1][r],
                           tile[c0 + u * 4 + 2][r], tile[c0 + u * 4 + 3][r]);
    *(float4*)(W1T + ob + u * 4) = o;
  }
#pragma unroll
  for (int sl = 0; sl < 2; ++sl) {
    const int slot = tid + sl * 256;
    const int frag_loc = slot >> 6, lane = slot & 63;
    const int kc_loc = frag_loc >> 1, s_loc = frag_loc & 1;
    const int n_loc = s_loc * 32 + (lane & 31);
    const int k_base = kc_loc * 16 + (lane >> 5) * 8;
    uint4 hh, mm;
    unsigned* hw = (unsigned*)&hh;
    unsigned* mw = (unsigned*)&mm;
#pragma unroll
    for (int p = 0; p < 4; ++p)
      split_pair(tile[k_base + 2 * p][n_loc], tile[k_base + 2 * p + 1][n_loc],
                 hw[p], mw[p]);
    const size_t f = (size_t)((nb >> 5) + s_loc) * 256 + (kb >> 4) + kc_loc;
    pkh[f * 64 + lane] = hh;
    pkm[f * 64 + lane] = mm;
  }
}

// ---------------------------------------------------------------------------
// gemm_fast (R9 proven structure; K-loop reordered MFMA-first so the
// ds_read+MFMA burst issues right after the barrier and the split VALU of
// the next slice schedules into the MFMA shadow).
// Block 128M x 128N, 4 waves (2m x 2n), BK=32, dbuf A LDS, B reg pingpong.
// ---------------------------------------------------------------------------
__global__ __launch_bounds__(256, 2) void gemm_fast(const float* __restrict__ x,
                                                    const uint4* __restrict__ pkh,
                                                    const uint4* __restrict__ pkm,
                                                    const float* __restrict__ b1,
                                                    float* __restrict__ S,
                                                    unsigned* __restrict__ cnt,
                                                    unsigned* __restrict__ list) {
  __shared__ __attribute__((aligned(16))) char lds[32768];
  float* const dS = (float*)lds;

  const int tid = threadIdx.x;
  const int lane = tid & 63, wid = tid >> 6;
  const int lr = lane & 31;
  const int wm = (wid & 1) * 64;
  const int wq = wid >> 1;

  const int id = blockIdx.x;
  const int xcd = id & 7, sq = id >> 3;
  const int m_blk = xcd * 16 + (sq >> 2);
  const int n_blk = sq & 3;
  const int bm = m_blk * 128, bn = n_blk * 128;

  const int ar = tid >> 1, akh = tid & 1;
  const float* Ap = x + (size_t)(bm + ar) * K1 + akh * 16;
  const int wr0 = (akh * 4 + (ar >> 5)) * 1024 + (ar & 31) * 16;

  const int s0 = n_blk * 4 + wq * 2;
  const uint4* pbh[2][2];
  const uint4* pbm[2][2];
#pragma unroll
  for (int kh = 0; kh < 2; ++kh)
#pragma unroll
    for (int nt = 0; nt < 2; ++nt) {
      const size_t base = ((size_t)(s0 + nt) * 256 + kh) * 64 + lane;
      pbh[kh][nt] = pkh + base;
      pbm[kh][nt] = pkm + base;
    }

  f32x16 acc[2][2] = {};
  float4 av[4];
  uint4 bch[2][2], bcm[2][2], bnh[2][2], bnm[2][2];

#pragma unroll
  for (int u = 0; u < 4; ++u) av[u] = *(const float4*)(Ap + u * 4);
#pragma unroll
  for (int kh = 0; kh < 2; ++kh)
#pragma unroll
    for (int nt = 0; nt < 2; ++nt) {
      bch[kh][nt] = pbh[kh][nt][0];
      bcm[kh][nt] = pbm[kh][nt][0];
      bnh[kh][nt] = pbh[kh][nt][32 * 4];
      bnm[kh][nt] = pbm[kh][nt][32 * 4];
    }

  // prologue: split slice 0 into buf0, prefetch slice 1
  {
    uint4 hi[2], mi[2];
    unsigned* hw = (unsigned*)hi;
    unsigned* mw = (unsigned*)mi;
#pragma unroll
    for (int u = 0; u < 4; ++u) {
      split_pair(av[u].x, av[u].y, hw[2 * u], mw[2 * u]);
      split_pair(av[u].z, av[u].w, hw[2 * u + 1], mw[2 * u + 1]);
    }
    *(uint4*)(lds + wr0)              = hi[0];
    *(uint4*)(lds + wr0 + 512)        = hi[1];
    *(uint4*)(lds + 8192 + wr0)       = mi[0];
    *(uint4*)(lds + 8192 + wr0 + 512) = mi[1];
#pragma unroll
    for (int u = 0; u < 4; ++u) av[u] = *(const float4*)(Ap + 32 + u * 4);
  }

  for (int k0 = 0; k0 < K1; k0 += 32) {
    const int cur = (k0 >> 5) & 1;
    char* const bufc = lds + cur * 16384;
    char* const bufn = lds + (cur ^ 1) * 16384;
    __syncthreads();

    // MFMA section FIRST: ds_reads of bufc can issue immediately post-barrier
#pragma unroll
    for (int kh = 0; kh < 2; ++kh) {
#pragma unroll
      for (int mt = 0; mt < 2; ++mt) {
        const int region = (kh * 4 + (wm >> 5) + mt) * 1024 + lane * 16;
        bf16x8 ah = *(const bf16x8*)(bufc + region);
        bf16x8 am = *(const bf16x8*)(bufc + 8192 + region);
#pragma unroll
        for (int nt = 0; nt < 2; ++nt) {
          const bf16x8 vbh = __builtin_bit_cast(bf16x8, bch[kh][nt]);
          const bf16x8 vbm = __builtin_bit_cast(bf16x8, bcm[kh][nt]);
          acc[mt][nt] = __builtin_amdgcn_mfma_f32_32x32x16_bf16(am, vbh, acc[mt][nt], 0, 0, 0);
          acc[mt][nt] = __builtin_amdgcn_mfma_f32_32x32x16_bf16(ah, vbm, acc[mt][nt], 0, 0, 0);
          acc[mt][nt] = __builtin_amdgcn_mfma_f32_32x32x16_bf16(ah, vbh, acc[mt][nt], 0, 0, 0);
        }
      }
    }

    // split next slice + write into bufn (fills the MFMA shadow)
    if (k0 + 32 < K1) {
      uint4 hi[2], mi[2];
      unsigned* hw = (unsigned*)hi;
      unsigned* mw = (unsigned*)mi;
#pragma unroll
      for (int u = 0; u < 4; ++u) {
        split_pair(av[u].x, av[u].y, hw[2 * u], mw[2 * u]);
        split_pair(av[u].z, av[u].w, hw[2 * u + 1], mw[2 * u + 1]);
      }
      *(uint4*)(bufn + wr0)              = hi[0];
      *(uint4*)(bufn + wr0 + 512)        = hi[1];
      *(uint4*)(bufn + 8192 + wr0)       = mi[0];
      *(uint4*)(bufn + 8192 + wr0 + 512) = mi[1];
    }
    if (k0 + 64 < K1) {
#pragma unroll
      for (int u = 0; u < 4; ++u) av[u] = *(const float4*)(Ap + k0 + 64 + u * 4);
    }

    // rotate B, prefetch next
#pragma unroll
    for (int kh = 0; kh < 2; ++kh)
#pragma unroll
      for (int nt = 0; nt < 2; ++nt) {
        bch[kh][nt] = bnh[kh][nt];
        bcm[kh][nt] = bnm[kh][nt];
      }
    if (k0 + 64 < K1) {
      const int off = (k0 + 64) * 4;
#pragma unroll
      for (int kh = 0; kh < 2; ++kh)
#pragma unroll
        for (int nt = 0; nt < 2; ++nt) {
          bnh[kh][nt] = pbh[kh][nt][off];
          bnm[kh][nt] = pbm[kh][nt][off];
        }
    }
  }

  // Epilogue: per 64-row half (one batch), stage y f32, fp32 LIF1 + flagging.
#pragma unroll
  for (int half = 0; half < 2; ++half) {
    __syncthreads();
    if ((wid & 1) == half) {
      const int lhi = lane >> 5;
#pragma unroll
      for (int mt = 0; mt < 2; ++mt)
#pragma unroll
        for (int nt = 0; nt < 2; ++nt)
#pragma unroll
          for (int r = 0; r < 16; ++r) {
            const int row = mt * 32 + (r & 3) + 8 * (r >> 2) + 4 * lhi;
            const int col = wq * 64 + nt * 32 + lr;
            dS[row * 128 + col] = acc[mt][nt][r];
          }
    }
    __syncthreads();
    if (tid < 128) {
      const int n = tid;
      const int b = m_blk * 2 + half;
      const float bias = b1[bn + n];
      float mem = 0.0f, spk = 0.0f, mn = 1e9f;
      for (int t = 0; t < TT; ++t) {
        const float y = dS[t * 128 + n] + bias;
        mem = mem * 0.5f * (1.0f - spk) + y;
        const float d = mem - 1.0f;
        mn = fminf(mn, fabsf(d));
        spk = (d > 0.0f) ? 1.0f : 0.0f;
        S[((size_t)(b * TT + t)) * N1 + bn + n] = spk;
      }
      if (mn < EPS) {
        unsigned idx = atomicAdd(cnt, 1u);
        if (idx < CAP) list[idx] = ((unsigned)b << 16) | (unsigned)(bn + n);
      }
    }
  }
}

// ---------------------------------------------------------------------------
// fixup_dots: (entry, quarter) work items; coalesced fp64 dot rows -> yfix.
// ---------------------------------------------------------------------------
__global__ __launch_bounds__(256) void fixup_dots(const float* __restrict__ x,
                                                  const float* __restrict__ W1T,
                                                  const unsigned* __restrict__ cnt,
                                                  const unsigned* __restrict__ list,
                                                  double* __restrict__ yfix) {
  const int tid = threadIdx.x;
  const int lane = tid & 63, w = tid >> 6;
  const int count = (int)min(*cnt, CAP);

  for (int item = blockIdx.x; item < count * 4; item += gridDim.x) {
    const int e = item >> 2, quarter = item & 3;
    const unsigned ent = list[e];
    const int b = (int)(ent >> 16), n = (int)(ent & 0xffffu);
    const float4* wr = (const float4*)(W1T + (size_t)n * K1);
#pragma unroll
    for (int i = 0; i < 4; ++i) {
      const int t = quarter * 16 + w * 4 + i;
      const float4* xr = (const float4*)(x + ((size_t)(b * TT + t)) * K1);
      double p = 0.0;
#pragma unroll
      for (int j = 0; j < 16; ++j) {
        const float4 xv = xr[lane + 64 * j];
        const float4 wv = wr[lane + 64 * j];
        p += (double)xv.x * (double)wv.x + (double)xv.y * (double)wv.y +
             (double)xv.z * (double)wv.z + (double)xv.w * (double)wv.w;
      }
#pragma unroll
      for (int off = 1; off < 64; off <<= 1) p += __shfl_xor(p, off);
      if (lane == 0) yfix[(size_t)e * TT + t] = p;
    }
  }
}

__global__ __launch_bounds__(256) void fixup_apply(const double* __restrict__ yfix,
                                                   const float* __restrict__ b1,
                                                   const unsigned* __restrict__ cnt,
                                                   const unsigned* __restrict__ list,
                                                   float* __restrict__ S) {
  const int count = (int)min(*cnt, CAP);
  for (int e = blockIdx.x * 256 + threadIdx.x; e < count; e += gridDim.x * 256) {
    const unsigned ent = list[e];
    const int b = (int)(ent >> 16), n = (int)(ent & 0xffffu);
    double mem = 0.0, spk = 0.0;
    const double bias = (double)b1[n];
    for (int t = 0; t < TT; ++t) {
      const double y = yfix[(size_t)e * TT + t] + bias;
      mem = mem * 0.5 * (1.0 - spk) + y;
      spk = (mem > 1.0) ? 1.0 : 0.0;
      S[((size_t)(b * TT + t)) * N1 + n] = (float)spk;
    }
  }
}

__global__ __launch_bounds__(64) void prep_w2(const float* __restrict__ W2,
                                              uint4* __restrict__ p2h,
                                              uint4* __restrict__ p2m,
                                              uint4* __restrict__ p2l) {
  const int f = blockIdx.x;
  const int lane = threadIdx.x;
  const int s = f >> 5, kc = f & 31;
  const int n = s * 32 + (lane & 31);
  const int kb = kc * 16 + (lane >> 5) * 8;
  U8 hh, mm, ll;
#pragma unroll
  for (int j = 0; j < 8; ++j) {
    const float w = (n < NC) ? W2[(size_t)(kb + j) * NC + n] : 0.0f;
    __bf16 h = (__bf16)w;  float r1 = w - (float)h;
    __bf16 m = (__bf16)r1; float r2 = r1 - (float)m;
    __bf16 l = (__bf16)r2;
    BC ch; ch.b = h; BC cm; cm.b = m; BC cl; cl.b = l;
    hh.u[j] = ch.s; mm.u[j] = cm.s; ll.u[j] = cl.s;
  }
  p2h[(size_t)f * 64 + lane] = hh.v;
  p2m[(size_t)f * 64 + lane] = mm.v;
  p2l[(size_t)f * 64 + lane] = ll.v;
}

__global__ __launch_bounds__(256) void head_mfma(const float* __restrict__ S,
                                                 const uint4* __restrict__ p2h,
                                                 const uint4* __restrict__ p2m,
                                                 const uint4* __restrict__ p2l,
                                                 const float* __restrict__ b2,
                                                 float* __restrict__ ssum,
                                                 unsigned* __restrict__ cnt2,
                                                 unsigned* __restrict__ list2) {
  __shared__ __attribute__((aligned(16))) char lds[16384];
  float* const dS = (float*)lds;
  char* const buf = lds;

  const int tid = threadIdx.x;
  const int lane = tid & 63, wid = tid >> 6;
  const int wm2 = wid & 1, wn2 = wid >> 1;
  const int b = blockIdx.x;

  const int srow_ = tid >> 2, scol = (tid & 3) * 16;
  const float* Sp = S + ((size_t)(b * TT + srow_)) * N1 + scol;
  const int wb0 = srow_ * 128 + scol * 2;
  const int swz = (srow_ & 7) << 4;

  const int trow = wm2 * 32 + (lane & 31);
  const int aswz = (trow & 7) << 4;

  f32x16 acc = {};

  for (int step = 0; step < 8; ++step) {
    float4 v[4];
#pragma unroll
    for (int u = 0; u < 4; ++u) v[u] = *(const float4*)(Sp + step * 64 + u * 4);
    unsigned owv[8];
#pragma unroll
    for (int u = 0; u < 4; ++u) {
      unsigned d0, d1;
      split_pair(v[u].x, v[u].y, owv[2 * u], d0);
      split_pair(v[u].z, v[u].w, owv[2 * u + 1], d1);
      (void)d0; (void)d1;
    }
    uint4 o0 = make_uint4(owv[0], owv[1], owv[2], owv[3]);
    uint4 o1 = make_uint4(owv[4], owv[5], owv[6], owv[7]);
    __syncthreads();
    *(uint4*)(buf + ((wb0)      ^ swz)) = o0;
    *(uint4*)(buf + ((wb0 + 16) ^ swz)) = o1;
    __syncthreads();

#pragma unroll
    for (int kcl = 0; kcl < 4; ++kcl) {
      const int abyte = (trow * 128 + kcl * 32 + (lane >> 5) * 16) ^ aswz;
      const bf16x8 af = *(const bf16x8*)(buf + abyte);
      const size_t fidx = ((size_t)wn2 * 32 + step * 4 + kcl) * 64 + lane;
      const bf16x8 bh = __builtin_bit_cast(bf16x8, p2h[fidx]);
      const bf16x8 bm = __builtin_bit_cast(bf16x8, p2m[fidx]);
      const bf16x8 bl = __builtin_bit_cast(bf16x8, p2l[fidx]);
      acc = __builtin_amdgcn_mfma_f32_32x32x16_bf16(af, bl, acc, 0, 0, 0);
      acc = __builtin_amdgcn_mfma_f32_32x32x16_bf16(af, bm, acc, 0, 0, 0);
      acc = __builtin_amdgcn_mfma_f32_32x32x16_bf16(af, bh, acc, 0, 0, 0);
    }
  }

  __syncthreads();
#pragma unroll
  for (int r = 0; r < 16; ++r) {
    const int row = wm2 * 32 + (r & 3) + 8 * (r >> 2) + 4 * (lane >> 5);
    const int col = wn2 * 32 + (lane & 31);
    dS[row * 64 + col] = acc[r];
  }
  __syncthreads();

  if (tid < NC) {
    const float bias = b2[tid];
    float mem = 0.0f, spk = 0.0f, mn = 1e9f, ss = 0.0f;
    for (int t = 0; t < TT; ++t) {
      const float y = dS[t * 64 + tid] + bias;
      mem = mem * 0.5f * (1.0f - spk) + y;
      const float d = mem - 1.0f;
      mn = fminf(mn, fabsf(d));
      spk = (d > 0.0f) ? 1.0f : 0.0f;
      ss += spk;
    }
    ssum[b * NC + tid] = ss;
    if (mn < EPS2) {
      unsigned idx = atomicAdd(cnt2, 1u);
      if (idx < CAP2) list2[idx] = ((unsigned)b << 8) | (unsigned)tid;
    }
  }
}

__global__ __launch_bounds__(256) void fixup2(const float* __restrict__ S,
                                              const float* __restrict__ W2,
                                              const float* __restrict__ b2,
                                              const unsigned* __restrict__ cnt2,
                                              const unsigned* __restrict__ list2,
                                              float* __restrict__ ssum) {
  __shared__ float w2c[N1];
  __shared__ double y2[TT];
  const int tid = threadIdx.x;
  const int count = (int)min(*cnt2, CAP2);

  for (int e = blockIdx.x; e < count; e += gridDim.x) {
    const unsigned ent = list2[e];
    const int b = (int)(ent >> 8), c = (int)(ent & 255u);
    for (int h = tid; h < N1; h += 256) w2c[h] = W2[(size_t)h * NC + c];
    __syncthreads();
    const int t = tid >> 2, q = tid & 3;
    const float* sr = S + ((size_t)(b * TT + t)) * N1 + q * 128;
    double p = 0.0;
    for (int j = 0; j < 128; ++j) p += (double)sr[j] * (double)w2c[q * 128 + j];
    p += __shfl_xor(p, 1);
    p += __shfl_xor(p, 2);
    if (q == 0) y2[t] = p;
    __syncthreads();
    if (tid == 0) {
      double mem = 0.0, spk = 0.0, ss = 0.0;
      const double bias = (double)b2[c];
      for (int t2 = 0; t2 < TT; ++t2) {
        const double y = y2[t2] + bias;
        mem = mem * 0.5 * (1.0 - spk) + y;
        spk = (mem > 1.0) ? 1.0 : 0.0;
        ss += spk;
      }
      ssum[b * NC + c] = (float)ss;
    }
    __syncthreads();
  }
}

__global__ __launch_bounds__(256) void pool(const float* __restrict__ ssum,
                                            float* __restrict__ out) {
  const int i = blockIdx.x * 256 + threadIdx.x;
  if (i < 1024) {
    const int b = i >> 2, g = i & 3;
    double s = 0.0;
#pragma unroll
    for (int j = 0; j < 10; ++j) s += (double)ssum[b * NC + g * 10 + j];
    out[i] = (float)(s * (1.0 / 640.0));
  }
}

extern "C" void kernel_launch(void* const* d_in, const int* in_sizes, int n_in,
                              void* d_out, int out_size, void* d_ws, size_t ws_size,
                              hipStream_t stream) {
  const float* x  = (const float*)d_in[0];
  const float* W1 = (const float*)d_in[1];
  const float* b1 = (const float*)d_in[2];
  const float* W2 = (const float*)d_in[3];
  const float* b2 = (const float*)d_in[4];
  float* out = (float*)d_out;

  char* ws = (char*)d_ws;
  float*    Sb    = (float*)(ws + S_OFF);
  float*    W1T   = (float*)(ws + W1T_OFF);
  uint4*    pkh   = (uint4*)(ws + PKH_OFF);
  uint4*    pkm   = (uint4*)(ws + PKM_OFF);
  unsigned* cnt   = (unsigned*)(ws + CNT_OFF);
  unsigned* list  = (unsigned*)(ws + LIST_OFF);
  double*   yfix  = (double*)(ws + YFIX_OFF);
  uint4*    p2h   = (uint4*)(ws + W2PK_OFF);
  uint4*    p2m   = (uint4*)(ws + W2PK_OFF + 65536);
  uint4*    p2l   = (uint4*)(ws + W2PK_OFF + 131072);
  float*    ssumb = (float*)(ws + SSUM_OFF);
  unsigned* list2 = (unsigned*)(ws + LIST2_OFF);

  hipMemsetAsync(cnt, 0, 8, stream);
  prep<<<dim3(64, 8), dim3(256), 0, stream>>>(W1, W1T, pkh, pkm);
  gemm_fast<<<dim3(512), dim3(256), 0, stream>>>(x, pkh, pkm, b1, Sb, cnt, list);
  fixup_dots<<<dim3(2048), dim3(256), 0, stream>>>(x, W1T, cnt, list, yfix);
  fixup_apply<<<dim3(16), dim3(256), 0, stream>>>(yfix, b1, cnt, list, Sb);
  prep_w2<<<dim3(64), dim3(64), 0, stream>>>(W2, p2h, p2m, p2l);
  head_mfma<<<dim3(256), dim3(256), 0, stream>>>(Sb, p2h, p2m, p2l, b2, ssumb, cnt + 1, list2);
  fixup2<<<dim3(64), dim3(256), 0, stream>>>(Sb, W2, b2, cnt + 1, list2, ssumb);
  pool<<<dim3(4), dim3(256), 0, stream>>>(ssumb, out);
}

// Round 16
// 349.040 us; speedup vs baseline: 1.0987x; 1.0987x over previous
//
#include <hip/hip_runtime.h>

typedef __bf16 bf16x8 __attribute__((ext_vector_type(8)));
typedef float f32x16 __attribute__((ext_vector_type(16)));

constexpr int K1 = 4096;
constexpr int N1 = 512;
constexpr int TT = 64;
constexpr int NC = 40;
constexpr float EPS  = 1e-4f;
constexpr float EPS2 = 1e-5f;
constexpr unsigned CAP  = 8192;
constexpr unsigned CAP2 = 1024;

// ws layout (bytes) — high-water 50.46 MB (proven)
constexpr size_t S_OFF    = 0;
constexpr size_t W1T_OFF  = 33554432;
constexpr size_t PKH_OFF  = 41943040;
constexpr size_t PKM_OFF  = 46137344;
constexpr size_t CNT_OFF  = 50331648;
constexpr size_t LIST_OFF = 50331904;
constexpr size_t YFIX_OFF  = PKH_OFF;
constexpr size_t W2PK_OFF  = PKM_OFF;
constexpr size_t SSUM_OFF  = PKM_OFF + 196608;
constexpr size_t LIST2_OFF = PKM_OFF + 237568;

union U8 { ushort u[8]; uint4 v; };
union BC { __bf16 b; ushort s; };

__device__ __forceinline__ void split_pair(float f0, float f1,
                                           unsigned& hp, unsigned& mp) {
  asm("v_cvt_pk_bf16_f32 %0, %1, %2" : "=v"(hp) : "v"(f0), "v"(f1));
  unsigned h0b = hp << 16;
  unsigned h1b = hp & 0xFFFF0000u;
  float m0 = f0 - __builtin_bit_cast(float, h0b);
  float m1 = f1 - __builtin_bit_cast(float, h1b);
  asm("v_cvt_pk_bf16_f32 %0, %1, %2" : "=v"(mp) : "v"(m0), "v"(m1));
}

// ---------------------------------------------------------------------------
// prep: W1 -> W1T (f32 [n][k]) + MFMA B-frag-ordered bf16 hi/mid packs.
// ---------------------------------------------------------------------------
__global__ __launch_bounds__(256) void prep(const float* __restrict__ W1,
                                            float* __restrict__ W1T,
                                            uint4* __restrict__ pkh,
                                            uint4* __restrict__ pkm) {
  __shared__ float tile[64][65];
  const int tid = threadIdx.x;
  const int kb = blockIdx.x * 64;
  const int nb = blockIdx.y * 64;
  const int r  = tid >> 2;
  const int c0 = (tid & 3) * 16;
  const float4* src = (const float4*)(W1 + (size_t)(kb + r) * N1 + nb + c0);
#pragma unroll
  for (int u = 0; u < 4; ++u) {
    float4 v = src[u];
    tile[r][c0 + u * 4 + 0] = v.x;
    tile[r][c0 + u * 4 + 1] = v.y;
    tile[r][c0 + u * 4 + 2] = v.z;
    tile[r][c0 + u * 4 + 3] = v.w;
  }
  __syncthreads();
  const size_t ob = (size_t)(nb + r) * K1 + kb + c0;
#pragma unroll
  for (int u = 0; u < 4; ++u) {
    float4 o = make_float4(tile[c0 + u * 4 + 0][r], tile[c0 + u * 4 + 1][r],
                           tile[c0 + u * 4 + 2][r], tile[c0 + u * 4 + 3][r]);
    *(float4*)(W1T + ob + u * 4) = o;
  }
#pragma unroll
  for (int sl = 0; sl < 2; ++sl) {
    const int slot = tid + sl * 256;
    const int frag_loc = slot >> 6, lane = slot & 63;
    const int kc_loc = frag_loc >> 1, s_loc = frag_loc & 1;
    const int n_loc = s_loc * 32 + (lane & 31);
    const int k_base = kc_loc * 16 + (lane >> 5) * 8;
    uint4 hh, mm;
    unsigned* hw = (unsigned*)&hh;
    unsigned* mw = (unsigned*)&mm;
#pragma unroll
    for (int p = 0; p < 4; ++p)
      split_pair(tile[k_base + 2 * p][n_loc], tile[k_base + 2 * p + 1][n_loc],
                 hw[p], mw[p]);
    const size_t f = (size_t)((nb >> 5) + s_loc) * 256 + (kb >> 4) + kc_loc;
    pkh[f * 64 + lane] = hh;
    pkm[f * 64 + lane] = mm;
  }
}

// ---------------------------------------------------------------------------
// gemm_fast: R8/R9 proven structure and ORDER (split -> LDS write -> prefetch
// -> MFMA; one barrier per K-step; dbuf A LDS; B reg pingpong). 265 us,
// MfmaUtil ~33%. Six restructures (R10-R15) all regressed; compiler's
// schedule of this body is locally optimal.
// ---------------------------------------------------------------------------
__global__ __launch_bounds__(256, 2) void gemm_fast(const float* __restrict__ x,
                                                    const uint4* __restrict__ pkh,
                                                    const uint4* __restrict__ pkm,
                                                    const float* __restrict__ b1,
                                                    float* __restrict__ S,
                                                    unsigned* __restrict__ cnt,
                                                    unsigned* __restrict__ list) {
  __shared__ __attribute__((aligned(16))) char lds[32768];
  float* const dS = (float*)lds;

  const int tid = threadIdx.x;
  const int lane = tid & 63, wid = tid >> 6;
  const int lr = lane & 31;
  const int wm = (wid & 1) * 64;
  const int wq = wid >> 1;

  const int id = blockIdx.x;
  const int xcd = id & 7, sq = id >> 3;
  const int m_blk = xcd * 16 + (sq >> 2);
  const int n_blk = sq & 3;
  const int bm = m_blk * 128, bn = n_blk * 128;

  const int ar = tid >> 1, akh = tid & 1;
  const float* Ap = x + (size_t)(bm + ar) * K1 + akh * 16;
  const int wr0 = (akh * 4 + (ar >> 5)) * 1024 + (ar & 31) * 16;

  const int s0 = n_blk * 4 + wq * 2;
  const uint4* pbh[2][2];
  const uint4* pbm[2][2];
#pragma unroll
  for (int kh = 0; kh < 2; ++kh)
#pragma unroll
    for (int nt = 0; nt < 2; ++nt) {
      const size_t base = ((size_t)(s0 + nt) * 256 + kh) * 64 + lane;
      pbh[kh][nt] = pkh + base;
      pbm[kh][nt] = pkm + base;
    }

  f32x16 acc[2][2] = {};
  float4 av[4];
  uint4 bch[2][2], bcm[2][2], bnh[2][2], bnm[2][2];

#pragma unroll
  for (int u = 0; u < 4; ++u) av[u] = *(const float4*)(Ap + u * 4);
#pragma unroll
  for (int kh = 0; kh < 2; ++kh)
#pragma unroll
    for (int nt = 0; nt < 2; ++nt) {
      bch[kh][nt] = pbh[kh][nt][0];
      bcm[kh][nt] = pbm[kh][nt][0];
      bnh[kh][nt] = pbh[kh][nt][32 * 4];
      bnm[kh][nt] = pbm[kh][nt][32 * 4];
    }

  {
    uint4 hi[2], mi[2];
    unsigned* hw = (unsigned*)hi;
    unsigned* mw = (unsigned*)mi;
#pragma unroll
    for (int u = 0; u < 4; ++u) {
      split_pair(av[u].x, av[u].y, hw[2 * u], mw[2 * u]);
      split_pair(av[u].z, av[u].w, hw[2 * u + 1], mw[2 * u + 1]);
    }
    *(uint4*)(lds + wr0)              = hi[0];
    *(uint4*)(lds + wr0 + 512)        = hi[1];
    *(uint4*)(lds + 8192 + wr0)       = mi[0];
    *(uint4*)(lds + 8192 + wr0 + 512) = mi[1];
#pragma unroll
    for (int u = 0; u < 4; ++u) av[u] = *(const float4*)(Ap + 32 + u * 4);
  }

  for (int k0 = 0; k0 < K1; k0 += 32) {
    const int cur = (k0 >> 5) & 1;
    char* const bufc = lds + cur * 16384;
    char* const bufn = lds + (cur ^ 1) * 16384;
    __syncthreads();

    if (k0 + 32 < K1) {
      uint4 hi[2], mi[2];
      unsigned* hw = (unsigned*)hi;
      unsigned* mw = (unsigned*)mi;
#pragma unroll
      for (int u = 0; u < 4; ++u) {
        split_pair(av[u].x, av[u].y, hw[2 * u], mw[2 * u]);
        split_pair(av[u].z, av[u].w, hw[2 * u + 1], mw[2 * u + 1]);
      }
      *(uint4*)(bufn + wr0)              = hi[0];
      *(uint4*)(bufn + wr0 + 512)        = hi[1];
      *(uint4*)(bufn + 8192 + wr0)       = mi[0];
      *(uint4*)(bufn + 8192 + wr0 + 512) = mi[1];
    }
    if (k0 + 64 < K1) {
#pragma unroll
      for (int u = 0; u < 4; ++u) av[u] = *(const float4*)(Ap + k0 + 64 + u * 4);
    }

#pragma unroll
    for (int kh = 0; kh < 2; ++kh) {
#pragma unroll
      for (int mt = 0; mt < 2; ++mt) {
        const int region = (kh * 4 + (wm >> 5) + mt) * 1024 + lane * 16;
        bf16x8 ah = *(const bf16x8*)(bufc + region);
        bf16x8 am = *(const bf16x8*)(bufc + 8192 + region);
#pragma unroll
        for (int nt = 0; nt < 2; ++nt) {
          const bf16x8 vbh = __builtin_bit_cast(bf16x8, bch[kh][nt]);
          const bf16x8 vbm = __builtin_bit_cast(bf16x8, bcm[kh][nt]);
          acc[mt][nt] = __builtin_amdgcn_mfma_f32_32x32x16_bf16(am, vbh, acc[mt][nt], 0, 0, 0);
          acc[mt][nt] = __builtin_amdgcn_mfma_f32_32x32x16_bf16(ah, vbm, acc[mt][nt], 0, 0, 0);
          acc[mt][nt] = __builtin_amdgcn_mfma_f32_32x32x16_bf16(ah, vbh, acc[mt][nt], 0, 0, 0);
        }
      }
    }

#pragma unroll
    for (int kh = 0; kh < 2; ++kh)
#pragma unroll
      for (int nt = 0; nt < 2; ++nt) {
        bch[kh][nt] = bnh[kh][nt];
        bcm[kh][nt] = bnm[kh][nt];
      }
    if (k0 + 64 < K1) {
      const int off = (k0 + 64) * 4;
#pragma unroll
      for (int kh = 0; kh < 2; ++kh)
#pragma unroll
        for (int nt = 0; nt < 2; ++nt) {
          bnh[kh][nt] = pbh[kh][nt][off];
          bnm[kh][nt] = pbm[kh][nt][off];
        }
    }
  }

#pragma unroll
  for (int half = 0; half < 2; ++half) {
    __syncthreads();
    if ((wid & 1) == half) {
      const int lhi = lane >> 5;
#pragma unroll
      for (int mt = 0; mt < 2; ++mt)
#pragma unroll
        for (int nt = 0; nt < 2; ++nt)
#pragma unroll
          for (int r = 0; r < 16; ++r) {
            const int row = mt * 32 + (r & 3) + 8 * (r >> 2) + 4 * lhi;
            const int col = wq * 64 + nt * 32 + lr;
            dS[row * 128 + col] = acc[mt][nt][r];
          }
    }
    __syncthreads();
    if (tid < 128) {
      const int n = tid;
      const int b = m_blk * 2 + half;
      const float bias = b1[bn + n];
      float mem = 0.0f, spk = 0.0f, mn = 1e9f;
      for (int t = 0; t < TT; ++t) {
        const float y = dS[t * 128 + n] + bias;
        mem = mem * 0.5f * (1.0f - spk) + y;
        const float d = mem - 1.0f;
        mn = fminf(mn, fabsf(d));
        spk = (d > 0.0f) ? 1.0f : 0.0f;
        S[((size_t)(b * TT + t)) * N1 + bn + n] = spk;
      }
      if (mn < EPS) {
        unsigned idx = atomicAdd(cnt, 1u);
        if (idx < CAP) list[idx] = ((unsigned)b << 16) | (unsigned)(bn + n);
      }
    }
  }
}

// ---------------------------------------------------------------------------
// fixup_dots: (entry, quarter) work items; coalesced fp64 dot rows -> yfix.
// ---------------------------------------------------------------------------
__global__ __launch_bounds__(256) void fixup_dots(const float* __restrict__ x,
                                                  const float* __restrict__ W1T,
                                                  const unsigned* __restrict__ cnt,
                                                  const unsigned* __restrict__ list,
                                                  double* __restrict__ yfix) {
  const int tid = threadIdx.x;
  const int lane = tid & 63, w = tid >> 6;
  const int count = (int)min(*cnt, CAP);

  for (int item = blockIdx.x; item < count * 4; item += gridDim.x) {
    const int e = item >> 2, quarter = item & 3;
    const unsigned ent = list[e];
    const int b = (int)(ent >> 16), n = (int)(ent & 0xffffu);
    const float4* wr = (const float4*)(W1T + (size_t)n * K1);
#pragma unroll
    for (int i = 0; i < 4; ++i) {
      const int t = quarter * 16 + w * 4 + i;
      const float4* xr = (const float4*)(x + ((size_t)(b * TT + t)) * K1);
      double p = 0.0;
#pragma unroll
      for (int j = 0; j < 16; ++j) {
        const float4 xv = xr[lane + 64 * j];
        const float4 wv = wr[lane + 64 * j];
        p += (double)xv.x * (double)wv.x + (double)xv.y * (double)wv.y +
             (double)xv.z * (double)wv.z + (double)xv.w * (double)wv.w;
      }
#pragma unroll
      for (int off = 1; off < 64; off <<= 1) p += __shfl_xor(p, off);
      if (lane == 0) yfix[(size_t)e * TT + t] = p;
    }
  }
}

__global__ __launch_bounds__(256) void fixup_apply(const double* __restrict__ yfix,
                                                   const float* __restrict__ b1,
                                                   const unsigned* __restrict__ cnt,
                                                   const unsigned* __restrict__ list,
                                                   float* __restrict__ S) {
  const int count = (int)min(*cnt, CAP);
  for (int e = blockIdx.x * 256 + threadIdx.x; e < count; e += gridDim.x * 256) {
    const unsigned ent = list[e];
    const int b = (int)(ent >> 16), n = (int)(ent & 0xffffu);
    double mem = 0.0, spk = 0.0;
    const double bias = (double)b1[n];
    for (int t = 0; t < TT; ++t) {
      const double y = yfix[(size_t)e * TT + t] + bias;
      mem = mem * 0.5 * (1.0 - spk) + y;
      spk = (mem > 1.0) ? 1.0 : 0.0;
      S[((size_t)(b * TT + t)) * N1 + n] = (float)spk;
    }
  }
}

__global__ __launch_bounds__(64) void prep_w2(const float* __restrict__ W2,
                                              uint4* __restrict__ p2h,
                                              uint4* __restrict__ p2m,
                                              uint4* __restrict__ p2l) {
  const int f = blockIdx.x;
  const int lane = threadIdx.x;
  const int s = f >> 5, kc = f & 31;
  const int n = s * 32 + (lane & 31);
  const int kb = kc * 16 + (lane >> 5) * 8;
  U8 hh, mm, ll;
#pragma unroll
  for (int j = 0; j < 8; ++j) {
    const float w = (n < NC) ? W2[(size_t)(kb + j) * NC + n] : 0.0f;
    __bf16 h = (__bf16)w;  float r1 = w - (float)h;
    __bf16 m = (__bf16)r1; float r2 = r1 - (float)m;
    __bf16 l = (__bf16)r2;
    BC ch; ch.b = h; BC cm; cm.b = m; BC cl; cl.b = l;
    hh.u[j] = ch.s; mm.u[j] = cm.s; ll.u[j] = cl.s;
  }
  p2h[(size_t)f * 64 + lane] = hh.v;
  p2m[(size_t)f * 64 + lane] = mm.v;
  p2l[(size_t)f * 64 + lane] = ll.v;
}

__global__ __launch_bounds__(256) void head_mfma(const float* __restrict__ S,
                                                 const uint4* __restrict__ p2h,
                                                 const uint4* __restrict__ p2m,
                                                 const uint4* __restrict__ p2l,
                                                 const float* __restrict__ b2,
                                                 float* __restrict__ ssum,
                                                 unsigned* __restrict__ cnt2,
                                                 unsigned* __restrict__ list2) {
  __shared__ __attribute__((aligned(16))) char lds[16384];
  float* const dS = (float*)lds;
  char* const buf = lds;

  const int tid = threadIdx.x;
  const int lane = tid & 63, wid = tid >> 6;
  const int wm2 = wid & 1, wn2 = wid >> 1;
  const int b = blockIdx.x;

  const int srow_ = tid >> 2, scol = (tid & 3) * 16;
  const float* Sp = S + ((size_t)(b * TT + srow_)) * N1 + scol;
  const int wb0 = srow_ * 128 + scol * 2;
  const int swz = (srow_ & 7) << 4;

  const int trow = wm2 * 32 + (lane & 31);
  const int aswz = (trow & 7) << 4;

  f32x16 acc = {};

  for (int step = 0; step < 8; ++step) {
    float4 v[4];
#pragma unroll
    for (int u = 0; u < 4; ++u) v[u] = *(const float4*)(Sp + step * 64 + u * 4);
    unsigned owv[8];
#pragma unroll
    for (int u = 0; u < 4; ++u) {
      unsigned d0, d1;
      split_pair(v[u].x, v[u].y, owv[2 * u], d0);
      split_pair(v[u].z, v[u].w, owv[2 * u + 1], d1);
      (void)d0; (void)d1;
    }
    uint4 o0 = make_uint4(owv[0], owv[1], owv[2], owv[3]);
    uint4 o1 = make_uint4(owv[4], owv[5], owv[6], owv[7]);
    __syncthreads();
    *(uint4*)(buf + ((wb0)      ^ swz)) = o0;
    *(uint4*)(buf + ((wb0 + 16) ^ swz)) = o1;
    __syncthreads();

#pragma unroll
    for (int kcl = 0; kcl < 4; ++kcl) {
      const int abyte = (trow * 128 + kcl * 32 + (lane >> 5) * 16) ^ aswz;
      const bf16x8 af = *(const bf16x8*)(buf + abyte);
      const size_t fidx = ((size_t)wn2 * 32 + step * 4 + kcl) * 64 + lane;
      const bf16x8 bh = __builtin_bit_cast(bf16x8, p2h[fidx]);
      const bf16x8 bm = __builtin_bit_cast(bf16x8, p2m[fidx]);
      const bf16x8 bl = __builtin_bit_cast(bf16x8, p2l[fidx]);
      acc = __builtin_amdgcn_mfma_f32_32x32x16_bf16(af, bl, acc, 0, 0, 0);
      acc = __builtin_amdgcn_mfma_f32_32x32x16_bf16(af, bm, acc, 0, 0, 0);
      acc = __builtin_amdgcn_mfma_f32_32x32x16_bf16(af, bh, acc, 0, 0, 0);
    }
  }

  __syncthreads();
#pragma unroll
  for (int r = 0; r < 16; ++r) {
    const int row = wm2 * 32 + (r & 3) + 8 * (r >> 2) + 4 * (lane >> 5);
    const int col = wn2 * 32 + (lane & 31);
    dS[row * 64 + col] = acc[r];
  }
  __syncthreads();

  if (tid < NC) {
    const float bias = b2[tid];
    float mem = 0.0f, spk = 0.0f, mn = 1e9f, ss = 0.0f;
    for (int t = 0; t < TT; ++t) {
      const float y = dS[t * 64 + tid] + bias;
      mem = mem * 0.5f * (1.0f - spk) + y;
      const float d = mem - 1.0f;
      mn = fminf(mn, fabsf(d));
      spk = (d > 0.0f) ? 1.0f : 0.0f;
      ss += spk;
    }
    ssum[b * NC + tid] = ss;
    if (mn < EPS2) {
      unsigned idx = atomicAdd(cnt2, 1u);
      if (idx < CAP2) list2[idx] = ((unsigned)b << 8) | (unsigned)tid;
    }
  }
}

__global__ __launch_bounds__(256) void fixup2(const float* __restrict__ S,
                                              const float* __restrict__ W2,
                                              const float* __restrict__ b2,
                                              const unsigned* __restrict__ cnt2,
                                              const unsigned* __restrict__ list2,
                                              float* __restrict__ ssum) {
  __shared__ float w2c[N1];
  __shared__ double y2[TT];
  const int tid = threadIdx.x;
  const int count = (int)min(*cnt2, CAP2);

  for (int e = blockIdx.x; e < count; e += gridDim.x) {
    const unsigned ent = list2[e];
    const int b = (int)(ent >> 8), c = (int)(ent & 255u);
    for (int h = tid; h < N1; h += 256) w2c[h] = W2[(size_t)h * NC + c];
    __syncthreads();
    const int t = tid >> 2, q = tid & 3;
    const float* sr = S + ((size_t)(b * TT + t)) * N1 + q * 128;
    double p = 0.0;
    for (int j = 0; j < 128; ++j) p += (double)sr[j] * (double)w2c[q * 128 + j];
    p += __shfl_xor(p, 1);
    p += __shfl_xor(p, 2);
    if (q == 0) y2[t] = p;
    __syncthreads();
    if (tid == 0) {
      double mem = 0.0, spk = 0.0, ss = 0.0;
      const double bias = (double)b2[c];
      for (int t2 = 0; t2 < TT; ++t2) {
        const double y = y2[t2] + bias;
        mem = mem * 0.5 * (1.0 - spk) + y;
        spk = (mem > 1.0) ? 1.0 : 0.0;
        ss += spk;
      }
      ssum[b * NC + c] = (float)ss;
    }
    __syncthreads();
  }
}

__global__ __launch_bounds__(256) void pool(const float* __restrict__ ssum,
                                            float* __restrict__ out) {
  const int i = blockIdx.x * 256 + threadIdx.x;
  if (i < 1024) {
    const int b = i >> 2, g = i & 3;
    double s = 0.0;
#pragma unroll
    for (int j = 0; j < 10; ++j) s += (double)ssum[b * NC + g * 10 + j];
    out[i] = (float)(s * (1.0 / 640.0));
  }
}

extern "C" void kernel_launch(void* const* d_in, const int* in_sizes, int n_in,
                              void* d_out, int out_size, void* d_ws, size_t ws_size,
                              hipStream_t stream) {
  const float* x  = (const float*)d_in[0];
  const float* W1 = (const float*)d_in[1];
  const float* b1 = (const float*)d_in[2];
  const float* W2 = (const float*)d_in[3];
  const float* b2 = (const float*)d_in[4];
  float* out = (float*)d_out;

  char* ws = (char*)d_ws;
  float*    Sb    = (float*)(ws + S_OFF);
  float*    W1T   = (float*)(ws + W1T_OFF);
  uint4*    pkh   = (uint4*)(ws + PKH_OFF);
  uint4*    pkm   = (uint4*)(ws + PKM_OFF);
  unsigned* cnt   = (unsigned*)(ws + CNT_OFF);
  unsigned* list  = (unsigned*)(ws + LIST_OFF);
  double*   yfix  = (double*)(ws + YFIX_OFF);
  uint4*    p2h   = (uint4*)(ws + W2PK_OFF);
  uint4*    p2m   = (uint4*)(ws + W2PK_OFF + 65536);
  uint4*    p2l   = (uint4*)(ws + W2PK_OFF + 131072);
  float*    ssumb = (float*)(ws + SSUM_OFF);
  unsigned* list2 = (unsigned*)(ws + LIST2_OFF);

  hipMemsetAsync(cnt, 0, 8, stream);
  prep<<<dim3(64, 8), dim3(256), 0, stream>>>(W1, W1T, pkh, pkm);
  gemm_fast<<<dim3(512), dim3(256), 0, stream>>>(x, pkh, pkm, b1, Sb, cnt, list);
  fixup_dots<<<dim3(2048), dim3(256), 0, stream>>>(x, W1T, cnt, list, yfix);
  fixup_apply<<<dim3(16), dim3(256), 0, stream>>>(yfix, b1, cnt, list, Sb);
  prep_w2<<<dim3(64), dim3(64), 0, stream>>>(W2, p2h, p2m, p2l);
  head_mfma<<<dim3(256), dim3(256), 0, stream>>>(Sb, p2h, p2m, p2l, b2, ssumb, cnt + 1, list2);
  fixup2<<<dim3(64), dim3(256), 0, stream>>>(Sb, W2, b2, cnt + 1, list2, ssumb);
  pool<<<dim3(4), dim3(256), 0, stream>>>(ssumb, out);
}